// Round 13
// baseline (350.691 us; speedup 1.0000x reference)
//
#include <hip/hip_runtime.h>

// AttentionLayer: out = softmax(Q @ V^T) @ V ; B=4, SQ=SKV=4096, D=64, fp32.
//
// R12: attn reverted to EXACT R8 structure (best: 44.5us attn; transposed
// S^T = V·Q^T, K=16 PV from C-frags, per-lane softmax, dbuf LDS, one
// barrier/iter, staging loads top / stores end, launch_bounds(256,3)).
// NEW: combine kernel FUSED into attn as a split-K fixup — total-attn has
// been a constant ~58-64us across all rounds regardless of S/prep/combine
// size, pointing at fixed per-kernel cost, not compute. Last block per tile
// (device-scope atomic counter, zeroed by prep which precedes in-stream)
// rescales+normalizes the S partials and writes out. __threadfence() before
// the atomic publishes po/pm/pl through L2->L3 (the cross-XCD coherence
// point); reader L1 is cold for those lines within the launch.

#define NB   4
#define SQ   4096
#define SKV  4096
#define DH   64
#define L2E  1.44269504088896340736f

typedef _Float16 half8 __attribute__((ext_vector_type(8)));
typedef _Float16 half4 __attribute__((ext_vector_type(4)));
typedef _Float16 half2v __attribute__((ext_vector_type(2)));
typedef float f32x4 __attribute__((ext_vector_type(4)));
typedef unsigned short u16;

#define MFMA16(a, b, c) __builtin_amdgcn_mfma_f32_16x16x16f16((a), (b), (c), 0, 0, 0)
#define MFMA32(a, b, c) __builtin_amdgcn_mfma_f32_16x16x32_f16((a), (b), (c), 0, 0, 0)

__device__ __forceinline__ u16 f2h(float f) {
  _Float16 h = (_Float16)f;
  return __builtin_bit_cast(u16, h);
}
__device__ __forceinline__ half2v pkrtz(float a, float b) {
  return __builtin_bit_cast(half2v, __builtin_amdgcn_cvt_pkrtz(a, b));
}

// ---------------------------------------------------------------- prep ----
// V fp32 -> vh fp16 [b][j][d], vt fp16 [b][d][j]; also zeroes the split-K
// counters (prep precedes attn in-stream, so zeroing is ordered).
__global__ __launch_bounds__(256) void prep_kernel(
    const float* __restrict__ V, u16* __restrict__ vh, u16* __restrict__ vt,
    unsigned* __restrict__ cnt) {
  __shared__ u16 ldsT[16 * 72];
  int blk = blockIdx.x;
  if (threadIdx.x == 0 && blk < NB * 32) cnt[blk] = 0;
  int b   = blk >> 8;
  int rem = blk & 255;
  int j0  = (rem >> 2) << 6;   // kv tile base
  int d0  = (rem & 3) << 4;    // d tile base
  int t   = threadIdx.x;
  int j   = t >> 2;            // 0..63
  int dc  = (t & 3) << 2;      // 0,4,8,12

  const float* src = V + ((size_t)(b * SKV) + j0 + j) * DH + d0 + dc;
  float4 v4 = *(const float4*)src;
  u16 h[4] = {f2h(v4.x), f2h(v4.y), f2h(v4.z), f2h(v4.w)};
  unsigned p0 = (unsigned)h[0] | ((unsigned)h[1] << 16);
  unsigned p1 = (unsigned)h[2] | ((unsigned)h[3] << 16);
  size_t go = ((size_t)(b * SKV) + j0 + j) * DH + d0 + dc;
  *(uint2*)(vh + go) = make_uint2(p0, p1);

#pragma unroll
  for (int k = 0; k < 4; ++k) ldsT[(dc + k) * 72 + j] = h[k];
  __syncthreads();

  int dl = t >> 4;             // 0..15
  int jc = (t & 15) << 2;      // 0..60
  u16 tr[4];
#pragma unroll
  for (int k = 0; k < 4; ++k) tr[k] = ldsT[dl * 72 + jc + k];
  unsigned q0 = (unsigned)tr[0] | ((unsigned)tr[1] << 16);
  unsigned q1 = (unsigned)tr[2] | ((unsigned)tr[3] << 16);
  *(uint2*)(vt + ((size_t)(b * DH) + d0 + dl) * SKV + j0 + jc) = make_uint2(q0, q1);
}

// ---------------------------------------------------------------- attn ----
// grid NB*32*S blocks, 256 threads = 4 waves * 32 q-cols (2 sets of 16).
__global__ __launch_bounds__(256, 3) void attn_kernel(
    const float* __restrict__ Q,
    const u16* __restrict__ vh,
    const u16* __restrict__ vt,
    u16* __restrict__ po,    // [NB*32*S][128 q][64 d] fp16 unnormalized O
    float* __restrict__ pm,  // [NB*32*S][128] running max (log2 domain)
    float* __restrict__ pl,  // [NB*32*S][128] running sum
    float* __restrict__ out,
    unsigned* __restrict__ cnt,
    int S, int kvLen) {
  // [buf][0 = V tile [kv][d], 1 = V^T tile [d][kv]], stride 72 (pad)
  __shared__ __align__(16) u16 lds[2][2][64 * 72];
  __shared__ unsigned lastFlag;

  int blk  = blockIdx.x;
  int tile = blk / S;          // b*32 + qtile
  int s    = blk - tile * S;
  int b    = tile >> 5;
  int q0   = (tile & 31) << 7;
  int kv0  = s * kvLen;
  int t    = threadIdx.x;
  int wave = t >> 6;
  int lane = t & 63;
  int col  = lane & 15;
  int quad = lane >> 4;
  int qw   = q0 + (wave << 5);

  // ---- Q fragments as B-operand (n=lane&15=q, k=quad*8+j), log2e folded
  half8 qf[2][2];
#pragma unroll
  for (int set = 0; set < 2; ++set) {
#pragma unroll
    for (int kc = 0; kc < 2; ++kc) {
      const float* qp = Q + ((size_t)(b * SQ) + qw + set * 16 + col) * DH +
                        kc * 32 + (quad << 3);
      float4 a0 = *(const float4*)qp;
      float4 a1 = *(const float4*)(qp + 4);
      half8 h;
      h[0] = (_Float16)(a0.x * L2E); h[1] = (_Float16)(a0.y * L2E);
      h[2] = (_Float16)(a0.z * L2E); h[3] = (_Float16)(a0.w * L2E);
      h[4] = (_Float16)(a1.x * L2E); h[5] = (_Float16)(a1.y * L2E);
      h[6] = (_Float16)(a1.z * L2E); h[7] = (_Float16)(a1.w * L2E);
      qf[set][kc] = h;
    }
  }

  f32x4 o[2][4];               // O^T frags: [set][d-block], row=d, col=q
  float m_r[2] = {-1e30f, -1e30f};
  float l_r[2] = {0.f, 0.f};   // per-lane partial (this quad's kv rows)
#pragma unroll
  for (int set = 0; set < 2; ++set)
#pragma unroll
    for (int nf = 0; nf < 4; ++nf) o[set][nf] = (f32x4){0.f, 0.f, 0.f, 0.f};

  int sr = t >> 2;             // staging row 0..63
  int sc = (t & 3) << 4;       // staging col chunk
  const u16* gv  = vh + (size_t)(b * SKV) * DH;
  const u16* gvt = vt + (size_t)(b * DH) * SKV;
  int l0 = sr * 72 + sc;

  // prologue: stage tile 0 into buf 0
  {
    size_t g  = (size_t)(kv0 + sr) * DH + sc;
    size_t gt = (size_t)sr * SKV + kv0 + sc;
    *(uint4*)(&lds[0][0][l0])     = *(const uint4*)(gv + g);
    *(uint4*)(&lds[0][0][l0 + 8]) = *(const uint4*)(gv + g + 8);
    *(uint4*)(&lds[0][1][l0])     = *(const uint4*)(gvt + gt);
    *(uint4*)(&lds[0][1][l0 + 8]) = *(const uint4*)(gvt + gt + 8);
  }

  int nIter = kvLen >> 6;
  int cur = 0;
  for (int it = 0; it < nIter; ++it) {
    __syncthreads();           // buf(cur) ready; all waves done with buf(cur^1)

    // ---- issue next-tile loads NOW: whole compute body hides the latency
    uint4 a0, a1, c0, c1;
    bool more = (it + 1) < nIter;
    if (more) {
      int j0n = kv0 + ((it + 1) << 6);
      size_t g  = (size_t)(j0n + sr) * DH + sc;
      size_t gt = (size_t)sr * SKV + j0n + sc;
      a0 = *(const uint4*)(gv + g);
      a1 = *(const uint4*)(gv + g + 8);
      c0 = *(const uint4*)(gvt + gt);
      c1 = *(const uint4*)(gvt + gt + 8);
    }

    const u16* sv  = &lds[cur][0][0];
    const u16* svt = &lds[cur][1][0];

    // ---- S^T = V @ Q^T (A = V tile from LDS, B = Q regs)
    f32x4 sf[2][4];
#pragma unroll
    for (int set = 0; set < 2; ++set)
#pragma unroll
      for (int nf = 0; nf < 4; ++nf) sf[set][nf] = (f32x4){0.f, 0.f, 0.f, 0.f};
#pragma unroll
    for (int nf = 0; nf < 4; ++nf) {
#pragma unroll
      for (int kc = 0; kc < 2; ++kc) {
        half8 av = *(const half8*)(sv + (nf * 16 + col) * 72 + kc * 32 + (quad << 3));
        sf[0][nf] = MFMA32(av, qf[0][kc], sf[0][nf]);
        sf[1][nf] = MFMA32(av, qf[1][kc], sf[1][nf]);
      }
    }

    // ---- online softmax (per-lane scalar state) + direct P^T B-frags
    half4 pf[2][4];
#pragma unroll
    for (int set = 0; set < 2; ++set) {
      float tm = sf[set][0][0];
#pragma unroll
      for (int nf = 0; nf < 4; ++nf)
#pragma unroll
        for (int r = 0; r < 4; ++r) tm = fmaxf(tm, sf[set][nf][r]);
      tm = fmaxf(tm, __shfl_xor(tm, 16, 64));
      tm = fmaxf(tm, __shfl_xor(tm, 32, 64));
      float mn = fmaxf(m_r[set], tm);
      float al = exp2f(m_r[set] - mn);
      m_r[set] = mn;
      float rs = 0.f;
#pragma unroll
      for (int nf = 0; nf < 4; ++nf) {
        float p0 = exp2f(sf[set][nf][0] - mn);
        float p1 = exp2f(sf[set][nf][1] - mn);
        float p2 = exp2f(sf[set][nf][2] - mn);
        float p3 = exp2f(sf[set][nf][3] - mn);
        rs += (p0 + p1) + (p2 + p3);
        half2v lo = pkrtz(p0, p1);
        half2v hi = pkrtz(p2, p3);
        pf[set][nf] = __builtin_shufflevector(lo, hi, 0, 1, 2, 3);
      }
      l_r[set] = l_r[set] * al + rs;
#pragma unroll
      for (int nf = 0; nf < 4; ++nf)
#pragma unroll
        for (int r = 0; r < 4; ++r) o[set][nf][r] *= al;
    }

    // ---- O^T += V^T @ P^T (K=16; P^T frags straight from C-layout)
#pragma unroll
    for (int kc4 = 0; kc4 < 4; ++kc4) {
#pragma unroll
      for (int nf2 = 0; nf2 < 4; ++nf2) {
        half4 avt = *(const half4*)(svt + (nf2 * 16 + col) * 72 + kc4 * 16 + (quad << 2));
        o[0][nf2] = MFMA16(avt, pf[0][kc4], o[0][nf2]);
        o[1][nf2] = MFMA16(avt, pf[1][kc4], o[1][nf2]);
      }
    }

    // ---- write staged regs -> other buffer (loads long since landed)
    if (more) {
      u16* dv  = &lds[cur ^ 1][0][0];
      u16* dvt = &lds[cur ^ 1][1][0];
      *(uint4*)(dv + l0)      = a0;
      *(uint4*)(dv + l0 + 8)  = a1;
      *(uint4*)(dvt + l0)     = c0;
      *(uint4*)(dvt + l0 + 8) = c1;
    }
    cur ^= 1;
  }

  // ---- epilogue: finish l across quads, transpose O^T -> po[q][d] via LDS
#pragma unroll
  for (int set = 0; set < 2; ++set) {
    l_r[set] += __shfl_xor(l_r[set], 16, 64);
    l_r[set] += __shfl_xor(l_r[set], 32, 64);
  }
  int pidx = tile * S + s;
  if (quad == 0) {
#pragma unroll
    for (int set = 0; set < 2; ++set) {
      int row = (wave << 5) + set * 16 + col;
      pm[(size_t)pidx * 128 + row] = m_r[set];
      pl[(size_t)pidx * 128 + row] = l_r[set];
    }
  }

  __syncthreads();             // done with tile buffers; reuse as 128x72 tile
  u16* tp = &lds[0][0][0];
#pragma unroll
  for (int set = 0; set < 2; ++set) {
    int q = (wave << 5) + set * 16 + col;
#pragma unroll
    for (int nf2 = 0; nf2 < 4; ++nf2) {
#pragma unroll
      for (int r2 = 0; r2 < 4; r2 += 2) {
        unsigned pk = (unsigned)f2h(o[set][nf2][r2]) |
                      ((unsigned)f2h(o[set][nf2][r2 + 1]) << 16);
        int d = nf2 * 16 + (quad << 2) + r2;
        *(unsigned*)(tp + q * 72 + d) = pk;
      }
    }
  }
  __syncthreads();
  {
    u16* pob = po + (size_t)pidx * 128 * 64;
    int q = t >> 1, hc = (t & 1) << 5;
    uint4 x0 = *(const uint4*)(tp + q * 72 + hc);
    uint4 x1 = *(const uint4*)(tp + q * 72 + hc + 8);
    uint4 x2 = *(const uint4*)(tp + q * 72 + hc + 16);
    uint4 x3 = *(const uint4*)(tp + q * 72 + hc + 24);
    *(uint4*)(pob + q * 64 + hc)      = x0;
    *(uint4*)(pob + q * 64 + hc + 8)  = x1;
    *(uint4*)(pob + q * 64 + hc + 16) = x2;
    *(uint4*)(pob + q * 64 + hc + 24) = x3;
  }

  // ---- split-K fixup: last block of this tile combines the S partials
  __threadfence();             // publish po/pm/pl to L3 (cross-XCD coherent)
  if (t == 0) lastFlag = atomicAdd(&cnt[tile], 1u);
  __syncthreads();
  if (lastFlag != (unsigned)(S - 1)) return;
  __threadfence();             // acquire side

#pragma unroll 1
  for (int p = 0; p < 4; ++p) {
    int row = (t >> 3) + (p << 5);   // 0..127
    int dc  = (t & 7) << 3;          // 0..56
    float mv[8], lv[8];
    float M = -1e30f;
    for (int ss = 0; ss < S; ++ss) {
      mv[ss] = pm[(size_t)(tile * S + ss) * 128 + row];
      lv[ss] = pl[(size_t)(tile * S + ss) * 128 + row];
      M = fmaxf(M, mv[ss]);
    }
    float L = 0.f, w[8];
    for (int ss = 0; ss < S; ++ss) {
      w[ss] = exp2f(mv[ss] - M);
      L += lv[ss] * w[ss];
    }
    float acc[8] = {0.f, 0.f, 0.f, 0.f, 0.f, 0.f, 0.f, 0.f};
    for (int ss = 0; ss < S; ++ss) {
      const u16* pp = po + (size_t)(tile * S + ss) * 8192 + row * 64 + dc;
      uint4 raw = *(const uint4*)pp;
      half8 x = __builtin_bit_cast(half8, raw);
#pragma unroll
      for (int k = 0; k < 8; ++k) acc[k] += w[ss] * (float)x[k];
    }
    float invL = 1.0f / L;
    float* op = out + ((size_t)tile * 128 + row) * 64 + dc;
    f32x4 o0 = (f32x4){acc[0], acc[1], acc[2], acc[3]};
    f32x4 o1 = (f32x4){acc[4], acc[5], acc[6], acc[7]};
    *(f32x4*)op       = o0 * invL;
    *(f32x4*)(op + 4) = o1 * invL;
  }
}

// -------------------------------------------------------------- launch ----
extern "C" void kernel_launch(void* const* d_in, const int* in_sizes, int n_in,
                              void* d_out, int out_size, void* d_ws, size_t ws_size,
                              hipStream_t stream) {
  const float* Q = (const float*)d_in[0];
  const float* V = (const float*)d_in[1];
  float* out = (float*)d_out;

  const size_t convBytes = (size_t)2 * NB * SKV * DH * 2;  // vh+vt = 4 MB
  auto partBytes = [](int S) {
    return (size_t)NB * 32 * S * ((size_t)128 * 64 * 2 + 128 * 8) + 1024;
  };
  int S = 8;
  while (S > 1 && ws_size < convBytes + partBytes(S)) S >>= 1;
  int kvLen = SKV / S;

  u16* vh = (u16*)d_ws;
  u16* vt = vh + (size_t)NB * SKV * DH;
  u16* po = vt + (size_t)NB * SKV * DH;
  float* pm = (float*)(po + (size_t)NB * 32 * S * 128 * 64);
  float* pl = pm + (size_t)NB * 32 * S * 128;
  unsigned* cnt = (unsigned*)(pl + (size_t)NB * 32 * S * 128);

  prep_kernel<<<NB * 256, 256, 0, stream>>>(V, vh, vt, cnt);
  attn_kernel<<<NB * 32 * S, 256, 0, stream>>>(Q, vh, vt, po, pm, pl, out, cnt,
                                               S, kvLen);
}

// Round 14
// 106.040 us; speedup vs baseline: 3.3072x; 3.3072x over previous
//
#include <hip/hip_runtime.h>

// AttentionLayer: out = softmax(Q @ V^T) @ V ; B=4, SQ=SKV=4096, D=64, fp32.
//
// R13: R8 skeleton (transposed S^T = V·Q^T, K=16 PV from C-frags, per-lane
// softmax, dbuf LDS, one barrier/iter) + occupancy restructure:
//  - M=16 q/wave (64-q blocks), S=4 -> grid 1024.
//  - DMA staging (global_load_lds w16, R10-proven): no staged VGPRs.
//  - Unpadded 32 KB LDS -> 5 blocks/CU (R8's 36.9 KB allowed only 4).
//  - vh: R10 XOR-chunk swizzle (chunk c at c^(j&7)) -> 2-way banks, free.
//  - vt: NEW kv-permuted layout: chunk h=(kc2*4+quad) holds kv =
//    kc2*32+(e>>2)*16+quad*4+(e&3), phys chunk = h^(d&7). One b128 read
//    feeds TWO K=16 PV MFMAs (was 2 b64s) -> 16 LDS reads/wave-tile vs 24.
// R12 lesson (journal): __threadfence per block = L2 writeback storm, 7x
// regression. No intra-launch cross-block visibility; combine is a kernel.

#define NB   4
#define SQ   4096
#define SKV  4096
#define DH   64
#define L2E  1.44269504088896340736f

typedef _Float16 half8 __attribute__((ext_vector_type(8)));
typedef _Float16 half4 __attribute__((ext_vector_type(4)));
typedef _Float16 half2v __attribute__((ext_vector_type(2)));
typedef float f32x4 __attribute__((ext_vector_type(4)));
typedef unsigned short u16;

#define MFMA16(a, b, c) __builtin_amdgcn_mfma_f32_16x16x16f16((a), (b), (c), 0, 0, 0)
#define MFMA32(a, b, c) __builtin_amdgcn_mfma_f32_16x16x32_f16((a), (b), (c), 0, 0, 0)

__device__ __forceinline__ u16 f2h(float f) {
  _Float16 h = (_Float16)f;
  return __builtin_bit_cast(u16, h);
}
__device__ __forceinline__ half2v pkrtz(float a, float b) {
  return __builtin_bit_cast(half2v, __builtin_amdgcn_cvt_pkrtz(a, b));
}

typedef __attribute__((address_space(1))) void gvoid;
typedef __attribute__((address_space(3))) void lvoid;
__device__ __forceinline__ void dma16(const u16* g, u16* l) {
  __builtin_amdgcn_global_load_lds((gvoid*)g, (lvoid*)l, 16, 0, 0);
}

// ---------------------------------------------------------------- prep ----
// V fp32 -> vh fp16 [b][j][d-chunks swizzled by j&7]
//        -> vt fp16 [b][d][per-64-tile: phys chunk h^(d&7), h=(kc2*4+quad),
//                    elem e: kv = kc2*32+(e>>2)*16+quad*4+(e&3)]
__global__ __launch_bounds__(256) void prep_kernel(
    const float* __restrict__ V, u16* __restrict__ vh, u16* __restrict__ vt) {
  __shared__ u16 ldsT[16 * 72];
  int blk = blockIdx.x;
  int b   = blk >> 8;
  int rem = blk & 255;
  int j0  = (rem >> 2) << 6;   // kv tile base
  int d0  = (rem & 3) << 4;    // d tile base
  int t   = threadIdx.x;
  int j   = t >> 2;            // 0..63
  int dc  = (t & 3) << 2;      // 0,4,8,12

  const float* src = V + ((size_t)(b * SKV) + j0 + j) * DH + d0 + dc;
  float4 v4 = *(const float4*)src;
  u16 h[4] = {f2h(v4.x), f2h(v4.y), f2h(v4.z), f2h(v4.w)};
  unsigned p0 = (unsigned)h[0] | ((unsigned)h[1] << 16);
  unsigned p1 = (unsigned)h[2] | ((unsigned)h[3] << 16);
  int dfull = d0 + dc;
  int physd = ((((dfull >> 3) ^ (j & 7)) << 3)) + (dfull & 7);
  *(uint2*)(vh + ((size_t)(b * SKV) + j0 + j) * DH + physd) = make_uint2(p0, p1);

#pragma unroll
  for (int k = 0; k < 4; ++k) ldsT[(dc + k) * 72 + j] = h[k];
  __syncthreads();

  int dl = t >> 4;             // 0..15
  int jc = (t & 15) << 2;      // 0..60 (4 consecutive kv)
  u16 tr[4];
#pragma unroll
  for (int k = 0; k < 4; ++k) tr[k] = ldsT[dl * 72 + jc + k];
  unsigned q0 = (unsigned)tr[0] | ((unsigned)tr[1] << 16);
  unsigned q1 = (unsigned)tr[2] | ((unsigned)tr[3] << 16);
  int d   = d0 + dl;
  int kc2 = jc >> 5;
  int g   = (jc >> 4) & 1;
  int qd  = (jc >> 2) & 3;
  int hp  = ((kc2 << 2) | qd) ^ (d & 7);
  *(uint2*)(vt + ((size_t)(b * DH) + d) * SKV + j0 + (hp << 3) + (g << 2)) =
      make_uint2(q0, q1);
}

// ---------------------------------------------------------------- attn ----
// grid NB*64*S blocks, 256 threads = 4 waves * 16 q-cols each (64 q/block).
__global__ __launch_bounds__(256, 4) void attn_kernel(
    const float* __restrict__ Q,
    const u16* __restrict__ vh,
    const u16* __restrict__ vt,
    u16* __restrict__ po,    // [NB*64*S][64 q][64 d] fp16 unnormalized O
    float* __restrict__ pm,  // [NB*64*S][64] running max (log2 domain)
    float* __restrict__ pl,  // [NB*64*S][64] running sum
    int S, int kvLen) {
  __shared__ __align__(16) u16 lds[2][2][4096];  // [buf][0=V,1=VT], 32 KB

  int blk  = blockIdx.x;
  int tile = blk / S;          // b*64 + qtile
  int s    = blk - tile * S;
  int b    = tile >> 6;
  int q0   = (tile & 63) << 6;
  int kv0  = s * kvLen;
  int t    = threadIdx.x;
  int wave = t >> 6;
  int lane = t & 63;
  int col  = lane & 15;
  int quad = lane >> 4;
  int qw   = q0 + (wave << 4);
  int c7   = col & 7;

  const u16* gv  = vh + (size_t)(b * SKV) * DH;
  const u16* gvt = vt + (size_t)(b * DH) * SKV;

  int r0 = t >> 3;             // DMA row 0..31 (second instr: +32)
  int c0 = (t & 7) << 3;       // DMA chunk elem offset
  int wb = wave << 9;          // wave-uniform LDS dest base (elems)

  // ---- Q fragment as B-operand (n=col=q, k=quad*8+j), log2e folded
  half8 qf[2];
#pragma unroll
  for (int kc = 0; kc < 2; ++kc) {
    const float* qp = Q + ((size_t)(b * SQ) + qw + col) * DH + kc * 32 + (quad << 3);
    float4 a0 = *(const float4*)qp;
    float4 a1 = *(const float4*)(qp + 4);
    half8 hq;
    hq[0] = (_Float16)(a0.x * L2E); hq[1] = (_Float16)(a0.y * L2E);
    hq[2] = (_Float16)(a0.z * L2E); hq[3] = (_Float16)(a0.w * L2E);
    hq[4] = (_Float16)(a1.x * L2E); hq[5] = (_Float16)(a1.y * L2E);
    hq[6] = (_Float16)(a1.z * L2E); hq[7] = (_Float16)(a1.w * L2E);
    qf[kc] = hq;
  }

  f32x4 o[4];                  // O^T frags: d = nf2*16+quad*4+r, q = col
#pragma unroll
  for (int nf = 0; nf < 4; ++nf) o[nf] = (f32x4){0.f, 0.f, 0.f, 0.f};
  float m_r = -1e30f, l_r = 0.f;

  // prologue: DMA tile 0 into buf 0 (drained by first barrier)
  dma16(gv + ((size_t)(kv0 + r0) << 6) + c0,       &lds[0][0][0] + wb);
  dma16(gv + ((size_t)(kv0 + r0 + 32) << 6) + c0,  &lds[0][0][0] + 2048 + wb);
  dma16(gvt + (size_t)r0 * SKV + kv0 + c0,         &lds[0][1][0] + wb);
  dma16(gvt + (size_t)(r0 + 32) * SKV + kv0 + c0,  &lds[0][1][0] + 2048 + wb);

  int nIter = kvLen >> 6;
  int cur = 0;
  for (int it = 0; it < nIter; ++it) {
    __syncthreads();           // drains prior DMA (vmcnt(0)) + buf handoff

    if ((it + 1) < nIter) {    // DMA next tile; hidden under this compute
      int j0n = kv0 + ((it + 1) << 6);
      u16* dv  = &lds[cur ^ 1][0][0];
      u16* dvt = &lds[cur ^ 1][1][0];
      dma16(gv + ((size_t)(j0n + r0) << 6) + c0,      dv + wb);
      dma16(gv + ((size_t)(j0n + r0 + 32) << 6) + c0, dv + 2048 + wb);
      dma16(gvt + (size_t)r0 * SKV + j0n + c0,        dvt + wb);
      dma16(gvt + (size_t)(r0 + 32) * SKV + j0n + c0, dvt + 2048 + wb);
    }

    const u16* sv = &lds[cur][0][0];
    const u16* st = &lds[cur][1][0];

    // ---- S^T = V @ Q^T : sf[nf] covers kv = nf*16 + quad*4 + r
    f32x4 sf[4];
#pragma unroll
    for (int nf = 0; nf < 4; ++nf) sf[nf] = (f32x4){0.f, 0.f, 0.f, 0.f};
#pragma unroll
    for (int nf = 0; nf < 4; ++nf) {
#pragma unroll
      for (int kc = 0; kc < 2; ++kc) {
        int ch = ((kc << 2) | quad) ^ c7;
        half8 av = *(const half8*)(sv + ((nf * 16 + col) << 6) + (ch << 3));
        sf[nf] = MFMA32(av, qf[kc], sf[nf]);
      }
    }

    // ---- online softmax (per-lane scalar state) -> P^T B-frags
    half4 pf[4];
    {
      float tm = sf[0][0];
#pragma unroll
      for (int nf = 0; nf < 4; ++nf)
#pragma unroll
        for (int r = 0; r < 4; ++r) tm = fmaxf(tm, sf[nf][r]);
      tm = fmaxf(tm, __shfl_xor(tm, 16, 64));
      tm = fmaxf(tm, __shfl_xor(tm, 32, 64));
      float mn = fmaxf(m_r, tm);
      float al = exp2f(m_r - mn);
      m_r = mn;
      float rs = 0.f;
#pragma unroll
      for (int nf = 0; nf < 4; ++nf) {
        float p0 = exp2f(sf[nf][0] - mn);
        float p1 = exp2f(sf[nf][1] - mn);
        float p2 = exp2f(sf[nf][2] - mn);
        float p3 = exp2f(sf[nf][3] - mn);
        rs += (p0 + p1) + (p2 + p3);
        half2v lo = pkrtz(p0, p1);
        half2v hi = pkrtz(p2, p3);
        pf[nf] = __builtin_shufflevector(lo, hi, 0, 1, 2, 3);
      }
      l_r = l_r * al + rs;
#pragma unroll
      for (int nf = 0; nf < 4; ++nf)
#pragma unroll
        for (int r = 0; r < 4; ++r) o[nf][r] *= al;
    }

    // ---- O^T += V^T @ P^T : one b128 feeds TWO K=16 MFMAs (kv-permuted vt)
#pragma unroll
    for (int kc2 = 0; kc2 < 2; ++kc2) {
#pragma unroll
      for (int nf2 = 0; nf2 < 4; ++nf2) {
        int ch = ((kc2 << 2) | quad) ^ c7;
        half8 w8 = *(const half8*)(st + ((nf2 * 16 + col) << 6) + (ch << 3));
        half4 wlo = __builtin_shufflevector(w8, w8, 0, 1, 2, 3);
        half4 whi = __builtin_shufflevector(w8, w8, 4, 5, 6, 7);
        o[nf2] = MFMA16(wlo, pf[kc2 * 2], o[nf2]);
        o[nf2] = MFMA16(whi, pf[kc2 * 2 + 1], o[nf2]);
      }
    }

    cur ^= 1;
  }

  // ---- epilogue: l reduce across quads, pm/pl, transpose O^T -> po[q][d]
  l_r += __shfl_xor(l_r, 16, 64);
  l_r += __shfl_xor(l_r, 32, 64);
  int pidx = tile * S + s;
  if (quad == 0) {
    pm[(size_t)pidx * 64 + (wave << 4) + col] = m_r;
    pl[(size_t)pidx * 64 + (wave << 4) + col] = l_r;
  }

  __syncthreads();             // tile buffers free; reuse as [64 q][72]
  u16* tp = &lds[0][0][0];
  {
    int qrow = (wave << 4) + col;
#pragma unroll
    for (int nf2 = 0; nf2 < 4; ++nf2) {
#pragma unroll
      for (int r2 = 0; r2 < 4; r2 += 2) {
        unsigned pk = (unsigned)f2h(o[nf2][r2]) |
                      ((unsigned)f2h(o[nf2][r2 + 1]) << 16);
        int d = nf2 * 16 + (quad << 2) + r2;
        *(unsigned*)(tp + qrow * 72 + d) = pk;
      }
    }
  }
  __syncthreads();
  {
    u16* pob = po + (size_t)pidx * 64 * 64;
    int q = t >> 2, hc = (t & 3) << 4;
    uint4 x0 = *(const uint4*)(tp + q * 72 + hc);
    uint4 x1 = *(const uint4*)(tp + q * 72 + hc + 8);
    *(uint4*)(pob + q * 64 + hc)     = x0;
    *(uint4*)(pob + q * 64 + hc + 8) = x1;
  }
}

// ------------------------------------------------------------- combine ----
// grid NB*SQ/32 blocks, 256 threads; thread = (q row, 8-d chunk).
__global__ __launch_bounds__(256) void combine_kernel(
    const u16* __restrict__ po,
    const float* __restrict__ pm,
    const float* __restrict__ pl,
    float* __restrict__ out, int S) {
  int t    = threadIdx.x;
  int rowg = blockIdx.x * 32 + (t >> 3);   // global q row
  int tile = rowg >> 6;
  int row  = rowg & 63;
  int dc   = (t & 7) << 3;

  float mv[8], lv[8];
  float M = -1e30f;
  for (int s = 0; s < S; ++s) {
    mv[s] = pm[(size_t)(tile * S + s) * 64 + row];
    lv[s] = pl[(size_t)(tile * S + s) * 64 + row];
    M = fmaxf(M, mv[s]);
  }
  float L = 0.f, w[8];
  for (int s = 0; s < S; ++s) {
    w[s] = exp2f(mv[s] - M);
    L += lv[s] * w[s];
  }
  float acc[8] = {0.f, 0.f, 0.f, 0.f, 0.f, 0.f, 0.f, 0.f};
  for (int s = 0; s < S; ++s) {
    const u16* p = po + (size_t)(tile * S + s) * 4096 + row * 64 + dc;
    uint4 raw = *(const uint4*)p;
    half8 x = __builtin_bit_cast(half8, raw);
#pragma unroll
    for (int k = 0; k < 8; ++k) acc[k] += w[s] * (float)x[k];
  }
  float invL = 1.0f / L;
  float* op = out + (size_t)rowg * 64 + dc;
  f32x4 o0 = (f32x4){acc[0], acc[1], acc[2], acc[3]};
  f32x4 o1 = (f32x4){acc[4], acc[5], acc[6], acc[7]};
  *(f32x4*)op       = o0 * invL;
  *(f32x4*)(op + 4) = o1 * invL;
}

// -------------------------------------------------------------- launch ----
extern "C" void kernel_launch(void* const* d_in, const int* in_sizes, int n_in,
                              void* d_out, int out_size, void* d_ws, size_t ws_size,
                              hipStream_t stream) {
  const float* Q = (const float*)d_in[0];
  const float* V = (const float*)d_in[1];
  float* out = (float*)d_out;

  const size_t convBytes = (size_t)2 * NB * SKV * DH * 2;  // vh+vt = 4 MB
  auto partBytes = [](int S) {
    return (size_t)NB * 64 * S * ((size_t)64 * 64 * 2 + 64 * 8);
  };
  int S = 4;
  while (S > 1 && ws_size < convBytes + partBytes(S)) S >>= 1;
  int kvLen = SKV / S;

  u16* vh = (u16*)d_ws;
  u16* vt = vh + (size_t)NB * SKV * DH;
  u16* po = vt + (size_t)NB * SKV * DH;
  float* pm = (float*)(po + (size_t)NB * 64 * S * 64 * 64);
  float* pl = pm + (size_t)NB * 64 * S * 64;

  prep_kernel<<<NB * 256, 256, 0, stream>>>(V, vh, vt);
  attn_kernel<<<NB * 64 * S, 256, 0, stream>>>(Q, vh, vt, po, pm, pl, S, kvLen);
  combine_kernel<<<NB * SQ / 32, 256, 0, stream>>>(po, pm, pl, out, S);
}